// Round 11
// baseline (909.017 us; speedup 1.0000x reference)
//
#include <hip/hip_runtime.h>
#include <math.h>
#include <stdint.h>

#define BB 128   // batch
#define SS 128   // seq len
#define EE 300   // embed dim
#define HH 256   // per-direction hidden
#define G4 1024  // 4*HH gate width
#define TT 16    // tagset
#define NEGV -10000.0f
#define START_TAG 14
#define STOP_TAG 15

typedef float f32x4 __attribute__((ext_vector_type(4)));

__device__ __forceinline__ float sigm(float x) { return 1.0f / (1.0f + expf(-x)); }

__device__ __forceinline__ float4 shfl_xor4(float4 v, int m) {
  float4 r;
  r.x = __shfl_xor(v.x, m); r.y = __shfl_xor(v.y, m);
  r.z = __shfl_xor(v.z, m); r.w = __shfl_xor(v.w, m);
  return r;
}
__device__ __forceinline__ void add4(float4& a, const float4& b) {
  a.x += b.x; a.y += b.y; a.z += b.z; a.w += b.w;
}

// 32B LLC-coherent load of 4 stamped pairs (sc0+sc1 bypass L1/L2 -> device
// coherent point). Load/store class proven R5-R10 on this chip.
__device__ __forceinline__ void load_pairs8(const float* p, f32x4& a, f32x4& b) {
  asm volatile("global_load_dwordx4 %0, %2, off sc0 sc1\n\t"
               "global_load_dwordx4 %1, %2, off offset:16 sc0 sc1\n\t"
               "s_waitcnt vmcnt(0)"
               : "=&v"(a), "=&v"(b) : "v"(p) : "memory");
}

// Publish (h, stamp) as ONE 8B relaxed agent-scope atomic store: payload is
// self-validating; no producer-side drain/tag/fence needed.
__device__ __forceinline__ void store_pair_llc(float2* p, float h, int stamp) {
  uint64_t bits = ((uint64_t)(uint32_t)stamp << 32) | (uint64_t)__float_as_uint(h);
  __hip_atomic_store((uint64_t*)p, bits, __ATOMIC_RELAXED, __HIP_MEMORY_SCOPE_AGENT);
}

// ---------------- prep: weight transposes + bias folding + hpair zero ----------------
__global__ void k_prep(const float* __restrict__ Wih_f, const float* __restrict__ Whh_f,
                       const float* __restrict__ bih_f, const float* __restrict__ bhh_f,
                       const float* __restrict__ Wih_b, const float* __restrict__ Whh_b,
                       const float* __restrict__ bih_b, const float* __restrict__ bhh_b,
                       float* __restrict__ WihT, float* __restrict__ Whh4,
                       float* __restrict__ bsum, float* __restrict__ hpairz) {
  int id = blockIdx.x * blockDim.x + threadIdx.x;
  const int N1 = 2 * EE * G4;
  const int N2 = 2 * HH * G4;
  const int N3 = 2 * G4;
  const int N4 = 3 * 2 * BB * HH * 2;   // hpair floats (stamps := 0 every launch)
  if (id < N1) {
    int d = id / (EE * G4); int r = id % (EE * G4);
    int e = r / G4; int j = r % G4;
    const float* W = d ? Wih_b : Wih_f;
    WihT[id] = W[j * EE + e];
  } else if (id < N1 + N2) {
    int t = id - N1;
    int d = t / (HH * G4); int r = t % (HH * G4);
    int k = r / G4; int q = r % G4; int u = q >> 2; int g = q & 3;
    const float* W = d ? Whh_b : Whh_f;
    Whh4[t] = W[(g * HH + u) * HH + k];
  } else if (id < N1 + N2 + N3) {
    int t = id - N1 - N2;
    int d = t / G4; int j = t % G4;
    bsum[t] = d ? (bih_b[j] + bhh_b[j]) : (bih_f[j] + bhh_f[j]);
  } else if (id < N1 + N2 + N3 + N4) {
    hpairz[id - N1 - N2 - N3] = 0.0f;
  }
}

// ---------------- input projection GEMM (gathered), e-blocked by 4 ----------------
__global__ void k_xproj(const int* __restrict__ sent, const float* __restrict__ emb,
                        const float* __restrict__ WihT, const float* __restrict__ bsum,
                        float4* __restrict__ xp4) {
  __shared__ __align__(16) float xs[16][EE];
  __shared__ int idxs[16];
  int blk = blockIdx.x;
  int d = blk >> 10;
  int tile = blk & 1023;
  int tid = threadIdx.x;
  if (tid < 16) {
    int sb = tile * 16 + tid;
    int s = sb >> 7, b = sb & 127;
    idxs[tid] = sent[b * SS + s];
  }
  __syncthreads();
  for (int t = tid; t < 16 * 75; t += 256) {
    int i = t / 75, e4 = t % 75;
    ((f32x4*)&xs[i][0])[e4] = ((const f32x4*)(emb + (size_t)idxs[i] * EE))[e4];
  }
  __syncthreads();

  const float* WT = WihT + (size_t)d * EE * G4;
  float acc0[16], acc1[16], acc2[16], acc3[16];
#pragma unroll
  for (int i = 0; i < 16; ++i) { acc0[i] = 0.f; acc1[i] = 0.f; acc2[i] = 0.f; acc3[i] = 0.f; }

  for (int e4 = 0; e4 < 75; ++e4) {
    f32x4 xv[16];
#pragma unroll
    for (int i = 0; i < 16; ++i)
      xv[i] = *(const f32x4*)&xs[i][e4 * 4];
    const float* rowb = WT + (size_t)e4 * 4 * G4;
#pragma unroll
    for (int j = 0; j < 4; ++j) {
      const float* row = rowb + (size_t)j * G4;
      float w0 = row[tid];
      float w1 = row[tid + 256];
      float w2 = row[tid + 512];
      float w3 = row[tid + 768];
#pragma unroll
      for (int i = 0; i < 16; ++i) {
        float x = xv[i][j];
        acc0[i] += w0 * x; acc1[i] += w1 * x; acc2[i] += w2 * x; acc3[i] += w3 * x;
      }
    }
  }
  float b0 = bsum[d * G4 + tid];
  float b1 = bsum[d * G4 + tid + 256];
  float b2 = bsum[d * G4 + tid + 512];
  float b3 = bsum[d * G4 + tid + 768];
#pragma unroll
  for (int i = 0; i < 16; ++i) {
    int sb = tile * 16 + i;
    int s = sb >> 7, b = sb & 127;
    xp4[(((size_t)d * SS + s) * BB + b) * HH + tid] =
        make_float4(acc0[i] + b0, acc1[i] + b1, acc2[i] + b2, acc3[i] + b3);
  }
}

// ---------------- recurrent LSTM: stamped pairs, 1 barrier/step, 2 blocks/CU ----------------
// grid 512: blk = d*256 + bg*8 + sl (bg in [0,32), 4 batches). 256 thr:
// tid = u*8 + kc. h(step) published as (h, step+1) 8B pairs at ring slot
// step%3 (fire-and-forget). Consumers poll the pairs they stage (one 32B
// sc0sc1 load = detect + data), sleep-throttled retry, then ONE stage barrier.
// LDS staging parity-double-buffered (WAR safety: step-t readers all pass the
// t+1 barrier before any t+2 write to the same parity). Ring depth 3 safe:
// any block <= group-min + 1 (staging gates advancement).
__global__ __launch_bounds__(256, 2) void k_recur(
    const float4* __restrict__ xp4, const float4* __restrict__ Wg,
    const float* __restrict__ h0, const float* __restrict__ c0,
    float2* __restrict__ hpair, float* __restrict__ hall) {
  __shared__ __align__(16) float hsh[2][4 * 288];  // h staging, kc-swizzled, dbuf

  int blk = blockIdx.x;
  int d = blk >> 8;
  int bg = (blk >> 3) & 31;
  int sl = blk & 7;
  int bbase = bg * 4;
  int tid = threadIdx.x;
  int u = tid >> 3, kc = tid & 7;
  int uglob = sl * 32 + u;

  // Whh slice -> registers: wreg[kk] = Whh4[d][kc*32+kk][uglob] (i,f,g,o)
  float4 wreg[32];
  {
    const float4* Wd = Wg + (size_t)d * (HH * HH) + (size_t)(kc * 32) * HH + uglob;
#pragma unroll
    for (int kk = 0; kk < 32; ++kk) wreg[kk] = Wd[(size_t)kk * HH];
  }
  // owner map for 4-batch reduce-scatter over kc (lanes kc and kc^4 duplicate)
  int b_own = ((kc & 1) << 1) | ((kc >> 1) & 1);
  float c_reg = c0[((size_t)d * BB + bbase + b_own) * HH + uglob];
  bool up0 = (kc & 1), up1 = (kc & 2);

  // staging: thread stages h[sb = tid>>6][k4 .. k4+3], k4 = (tid&63)*4
  int sb = tid >> 6;
  int k4 = (tid & 63) * 4;
  int ldoff = sb * 288 + (k4 >> 5) * 36 + (k4 & 31);

  for (int step = 0; step < SS; ++step) {
    int s = d ? (SS - 1 - step) : step;
    int pb = step & 1;
    // prefetch gate-input vec (h-independent), in flight during the wait
    float4 xg = xp4[(((size_t)d * SS + s) * BB + bbase + b_own) * HH + uglob];

    // ---- stage h(step-1): poll own stamped pairs (detect == data) ----
    float* ldst = &hsh[pb][ldoff];
    if (step == 0) {
      const float* ps = h0 + ((size_t)d * BB + bbase + sb) * HH + k4;
      *(f32x4*)ldst = *(const f32x4*)ps;
    } else {
      int slot_r = (step + 2) % 3;
      const float* ps = (const float*)(hpair +
          ((size_t)(slot_r * 2 + d) * BB + bbase + sb) * HH + k4);
      f32x4 v0, v1;
      load_pairs8(ps, v0, v1);
      while (__float_as_int(v0[1]) != step || __float_as_int(v0[3]) != step ||
             __float_as_int(v1[1]) != step || __float_as_int(v1[3]) != step) {
        __builtin_amdgcn_s_sleep(1);
        load_pairs8(ps, v0, v1);
      }
      f32x4 q = {v0[0], v0[2], v1[0], v1[2]};
      *(f32x4*)ldst = q;
    }
    __syncthreads();   // the ONLY barrier per step

    // ---- gate partials over this thread's 32-k chunk (4 batches) ----
    const float* hb = &hsh[pb][0];
    float4 a[4];
#pragma unroll
    for (int b = 0; b < 4; ++b) a[b] = make_float4(0.f, 0.f, 0.f, 0.f);
#pragma unroll
    for (int kk4 = 0; kk4 < 8; ++kk4) {
      float hvv[4][4];
#pragma unroll
      for (int b = 0; b < 4; ++b)
        *(f32x4*)&hvv[b][0] = *(const f32x4*)&hb[b * 288 + kc * 36 + kk4 * 4];
#pragma unroll
      for (int j = 0; j < 4; ++j) {
        float4 w = wreg[kk4 * 4 + j];
#pragma unroll
        for (int b = 0; b < 4; ++b) {
          float hj = hvv[b][j];
          a[b].x += w.x * hj; a[b].y += w.y * hj;
          a[b].z += w.z * hj; a[b].w += w.w * hj;
        }
      }
    }

    // ---- reduce-scatter over kc (3 rounds; kc^4 lanes duplicate, benign) ----
#pragma unroll
    for (int j = 0; j < 2; ++j) {
      float4 snd = up0 ? a[j] : a[j + 2];
      float4 rcv = shfl_xor4(snd, 1);
      if (!up0) add4(a[j], rcv); else add4(a[j + 2], rcv);
    }
    float4 v0 = up0 ? a[2] : a[0];
    float4 v1 = up0 ? a[3] : a[1];
    {
      float4 snd = up1 ? v0 : v1;
      float4 rcv = shfl_xor4(snd, 2);
      if (!up1) add4(v0, rcv); else add4(v1, rcv);
    }
    float4 keep = up1 ? v1 : v0;
    {
      float4 rcv = shfl_xor4(keep, 4);
      add4(keep, rcv);
    }

    // ---- nonlinearity + publish (fire-and-forget) ----
    float ii = keep.x + xg.x, ff = keep.y + xg.y;
    float gg = keep.z + xg.z, oo = keep.w + xg.w;
    c_reg = sigm(ff) * c_reg + sigm(ii) * tanhf(gg);
    float hn = sigm(oo) * tanhf(c_reg);

    if (kc < 4) {
      store_pair_llc(&hpair[((size_t)((step % 3) * 2 + d) * BB + bbase + b_own) * HH + uglob],
                     hn, step + 1);
      hall[(((size_t)d * SS + step) * BB + bbase + b_own) * HH + uglob] = hn;
    }
    // no trailing barrier: dbuf parity + next step's stage barrier order hsh reuse
  }
}

// ---------------- feats: featsF[b][s][t] = sum_u h cat dot W_out row ----------------
// grid 1024: blk = b*8 + sg (16 s each). 256 thr = 16 s_loc x 16 t.
__global__ void k_feats(const float* __restrict__ hall, const float* __restrict__ Wout,
                        float* __restrict__ featsF) {
  __shared__ __align__(16) float h2[16][516];   // concat(h_f, h_b) rows, padded
  int b = blockIdx.x >> 3;
  int sg = blockIdx.x & 7;
  int tid = threadIdx.x;

  for (int i = tid; i < 16 * 128; i += 256) {
    int r = i >> 7, seg = i & 127;
    int s = sg * 16 + r;
    f32x4 v;
    if (seg < 64)
      v = *(const f32x4*)&hall[(((size_t)0 * SS + s) * BB + b) * HH + seg * 4];
    else
      v = *(const f32x4*)&hall[(((size_t)1 * SS + (SS - 1 - s)) * BB + b) * HH + (seg - 64) * 4];
    *(f32x4*)&h2[r][seg * 4] = v;
  }
  __syncthreads();

  int sloc = tid >> 4, t = tid & 15;
  const float* wrow = Wout + t * 512;
  float p = 0.f;
  for (int j = 0; j < 128; ++j) {
    f32x4 hv = *(const f32x4*)&h2[sloc][j * 4];
    f32x4 wv = *(const f32x4*)&wrow[j * 4];
    p += hv[0] * wv[0] + hv[1] * wv[1] + hv[2] * wv[2] + hv[3] * wv[3];
  }
  featsF[((size_t)b * SS + sg * 16 + sloc) * TT + t] = p;
}

// ---------------- Viterbi (backpointers in LDS) ----------------
__global__ void k_viterbi(const float* __restrict__ featsF, const float* __restrict__ b_out,
                          const float* __restrict__ trans, float* __restrict__ out) {
  __shared__ float tr[TT * TT];
  __shared__ unsigned char bpl[16][SS][TT];   // 32 KB
  int tid = threadIdx.x;
  if (tid < TT * TT) tr[tid] = trans[tid];
  __syncthreads();

  int bg = tid >> 4;
  int next = tid & 15;
  int b = blockIdx.x * 16 + bg;
  float fv = (next == START_TAG) ? 0.0f : NEGV;
  float bo = b_out[next];
  const float* fF = featsF + (size_t)b * SS * TT;

  for (int s = 0; s < SS; ++s) {
    float best = -INFINITY; int arg = 0;
#pragma unroll
    for (int prev = 0; prev < TT; ++prev) {
      float fvp = __shfl(fv, prev, 16);
      float cand = fvp + tr[next * TT + prev];
      if (cand > best) { best = cand; arg = prev; }
    }
    float feat = fF[s * TT + next] + bo;
    fv = best + feat;
    bpl[bg][s][next] = (unsigned char)arg;
  }

  float bv = fv + tr[STOP_TAG * TT + next];
  int bi = next;
#pragma unroll
  for (int off = 8; off; off >>= 1) {
    float ov = __shfl_down(bv, off, 16);
    int oi = __shfl_down(bi, off, 16);
    if (ov > bv || (ov == bv && oi < bi)) { bv = ov; bi = oi; }
  }
  if (next == 0) {
    out[b] = bv;
    int tag = bi;
    float* po = out + BB + (size_t)b * SS;
    for (int s = SS - 1; s >= 0; --s) {
      po[s] = (float)tag;
      tag = bpl[bg][s][tag];
    }
  }
}

// ---------------- host ----------------
extern "C" void kernel_launch(void* const* d_in, const int* in_sizes, int n_in,
                              void* d_out, int out_size, void* d_ws, size_t ws_size,
                              hipStream_t stream) {
  const int*   sent  = (const int*)d_in[0];
  const float* emb   = (const float*)d_in[1];
  const float* Wih_f = (const float*)d_in[2];
  const float* Whh_f = (const float*)d_in[3];
  const float* bih_f = (const float*)d_in[4];
  const float* bhh_f = (const float*)d_in[5];
  const float* Wih_b = (const float*)d_in[6];
  const float* Whh_b = (const float*)d_in[7];
  const float* bih_b = (const float*)d_in[8];
  const float* bhh_b = (const float*)d_in[9];
  const float* Wout  = (const float*)d_in[10];
  const float* b_out = (const float*)d_in[11];
  const float* trans = (const float*)d_in[12];
  const float* h0    = (const float*)d_in[13];
  const float* c0    = (const float*)d_in[14];

  float* ws = (float*)d_ws;
  size_t off = 0;
  float* xproj  = ws + off; off += (size_t)2 * SS * BB * G4;          // 33,554,432 fl
  float* WihT   = ws + off; off += (size_t)2 * EE * G4;               //    614,400
  float* Whh4   = ws + off; off += (size_t)2 * HH * G4;               //    524,288
  float* bsum   = ws + off; off += (size_t)2 * G4;                    //      2,048
  float* featsF = ws + off; off += (size_t)BB * SS * TT;              //    262,144
  float* hall   = ws + off; off += (size_t)2 * SS * BB * HH;          //  8,388,608
  float* hpairf = ws + off; off += (size_t)3 * 2 * BB * HH * 2;       //    393,216

  const int NPREP = 2 * EE * G4 + 2 * HH * G4 + 2 * G4 + 3 * 2 * BB * HH * 2;
  k_prep<<<(NPREP + 255) / 256, 256, 0, stream>>>(Wih_f, Whh_f, bih_f, bhh_f,
                                                  Wih_b, Whh_b, bih_b, bhh_b,
                                                  WihT, Whh4, bsum, hpairf);
  k_xproj<<<2048, 256, 0, stream>>>(sent, emb, WihT, bsum, (float4*)xproj);

  {
    const float4* xp4c = (const float4*)xproj;
    const float4* Wgc  = (const float4*)Whh4;
    float2* hpair = (float2*)hpairf;
    void* kargs[] = {(void*)&xp4c, (void*)&Wgc, (void*)&h0, (void*)&c0,
                     (void*)&hpair, (void*)&hall};
    hipError_t e = hipLaunchCooperativeKernel(k_recur, dim3(512), dim3(256),
                                              kargs, 0, stream);
    if (e != hipSuccess) {
      // plain launch: 512 blocks fit 2/CU at our VGPR/LDS usage -> all resident
      k_recur<<<512, 256, 0, stream>>>(xp4c, Wgc, h0, c0, hpair, hall);
    }
  }

  k_feats<<<1024, 256, 0, stream>>>(hall, Wout, featsF);
  k_viterbi<<<8, 256, 0, stream>>>(featsF, b_out, trans, (float*)d_out);
}